// Round 1
// baseline (13202.541 us; speedup 1.0000x reference)
//
#include <hip/hip_runtime.h>
#include <math.h>

#define NX 192
#define NY 192
#define NZ 96
#define NV 4
#define VOL (NZ * NY * NX)      /* 3,538,944 */
#define NTOT (NV * VOL)         /* 14,155,776 */
#define YS NX
#define ZS (NY * NX)

// Extract foreground channel (c=1 of 2) for pred batches {0,1} -> vols 0,1
// and target batches {0,1} -> vols 2,3.
__global__ void extract_kernel(const float* __restrict__ pred,
                               const float* __restrict__ target,
                               float* __restrict__ cur) {
    int i = blockIdx.x * blockDim.x + threadIdx.x;
    if (i >= NTOT) return;
    int v = i / VOL;
    int p = i - v * VOL;
    int b = v & 1;
    const float* src = (v < 2) ? pred : target;
    cur[i] = src[(size_t)(b * 2 + 1) * VOL + p];
}

// soft_erode: min over 7-point cross (center + 6 axis neighbors),
// out-of-range treated as +inf (ignored).
__global__ void erode_kernel(const float* __restrict__ in,
                             float* __restrict__ out) {
    int i = blockIdx.x * blockDim.x + threadIdx.x;
    if (i >= NTOT) return;
    int x = i % NX;
    int t = i / NX;
    int y = t % NY;
    int z = (t / NY) % NZ;

    float m = in[i];
    if (x > 0)      m = fminf(m, in[i - 1]);
    if (x < NX - 1) m = fminf(m, in[i + 1]);
    if (y > 0)      m = fminf(m, in[i - YS]);
    if (y < NY - 1) m = fminf(m, in[i + YS]);
    if (z > 0)      m = fminf(m, in[i - ZS]);
    if (z < NZ - 1) m = fminf(m, in[i + ZS]);
    out[i] = m;
}

// Fused: D = dilate3x3x3(e); delta = relu(a - D); skel += relu(delta - skel*delta).
// With skel zero-initialized, round 0 yields skel = delta (the init step).
__global__ void update_kernel(const float* __restrict__ a,
                              const float* __restrict__ e,
                              float* __restrict__ skel) {
    int i = blockIdx.x * blockDim.x + threadIdx.x;
    if (i >= NTOT) return;
    int x = i % NX;
    int t = i / NX;
    int y = t % NY;
    int z = (t / NY) % NZ;

    float d = -INFINITY;
#pragma unroll
    for (int dz = -1; dz <= 1; ++dz) {
        int zz = z + dz;
        if (zz < 0 || zz >= NZ) continue;
#pragma unroll
        for (int dy = -1; dy <= 1; ++dy) {
            int yy = y + dy;
            if (yy < 0 || yy >= NY) continue;
            int base = i + dz * ZS + dy * YS;
            if (x > 0)      d = fmaxf(d, e[base - 1]);
            d = fmaxf(d, e[base]);
            if (x < NX - 1) d = fmaxf(d, e[base + 1]);
        }
    }
    float av = a[i];
    float delta = fmaxf(av - d, 0.0f);
    float s = skel[i];
    skel[i] = s + fmaxf(delta - s * delta, 0.0f);
}

// 4 sums: [0]=sum(skel_pred*target_fg) [1]=sum(skel_pred)
//         [2]=sum(skel_target*pred_fg) [3]=sum(skel_target)
__global__ void reduce_kernel(const float* __restrict__ skel,
                              const float* __restrict__ pred,
                              const float* __restrict__ target,
                              double* __restrict__ sums) {
    double acc[4] = {0.0, 0.0, 0.0, 0.0};
    for (int i = blockIdx.x * blockDim.x + threadIdx.x; i < NTOT;
         i += gridDim.x * blockDim.x) {
        int v = i / VOL;
        int p = i - v * VOL;
        int b = v & 1;
        size_t inoff = (size_t)(b * 2 + 1) * VOL + p;
        float s = skel[i];
        if (v < 2) {
            acc[0] += (double)(s * target[inoff]);
            acc[1] += (double)s;
        } else {
            acc[2] += (double)(s * pred[inoff]);
            acc[3] += (double)s;
        }
    }
    // wave64 reduce
#pragma unroll
    for (int off = 32; off > 0; off >>= 1) {
#pragma unroll
        for (int k = 0; k < 4; ++k) acc[k] += __shfl_down(acc[k], off, 64);
    }
    __shared__ double sm[4][4];
    int lane = threadIdx.x & 63;
    int wid = threadIdx.x >> 6;
    if (lane == 0) {
#pragma unroll
        for (int k = 0; k < 4; ++k) sm[wid][k] = acc[k];
    }
    __syncthreads();
    if (threadIdx.x == 0) {
#pragma unroll
        for (int k = 0; k < 4; ++k) {
            double t = sm[0][k] + sm[1][k] + sm[2][k] + sm[3][k];
            atomicAdd(&sums[k], t);
        }
    }
}

__global__ void final_kernel(const double* __restrict__ sums,
                             float* __restrict__ out) {
    if (threadIdx.x == 0 && blockIdx.x == 0) {
        const double SM = 1e-5;
        double tprec = (sums[0] + SM) / (sums[1] + SM);
        double tsens = (sums[2] + SM) / (sums[3] + SM);
        double cl = 2.0 * tprec * tsens / (tprec + tsens + SM);
        out[0] = (float)(1.0 - cl);
    }
}

extern "C" void kernel_launch(void* const* d_in, const int* in_sizes, int n_in,
                              void* d_out, int out_size, void* d_ws, size_t ws_size,
                              hipStream_t stream) {
    const float* pred = (const float*)d_in[0];
    const float* target = (const float*)d_in[1];
    float* out = (float*)d_out;

    float* cur = (float*)d_ws;
    float* ero = cur + NTOT;
    float* skel = ero + NTOT;
    double* sums = (double*)(skel + NTOT);

    hipMemsetAsync(skel, 0, (size_t)NTOT * sizeof(float), stream);
    hipMemsetAsync(sums, 0, 4 * sizeof(double), stream);

    const int threads = 256;
    const int grid = (NTOT + threads - 1) / threads;

    extract_kernel<<<grid, threads, 0, stream>>>(pred, target, cur);

    float* A = cur;
    float* E = ero;
    for (int it = 0; it <= 50; ++it) {
        erode_kernel<<<grid, threads, 0, stream>>>(A, E);
        update_kernel<<<grid, threads, 0, stream>>>(A, E, skel);
        float* tmp = A; A = E; E = tmp;
    }

    reduce_kernel<<<2048, 256, 0, stream>>>(skel, pred, target, sums);
    final_kernel<<<1, 64, 0, stream>>>(sums, out);
}

// Round 2
// 5117.581 us; speedup vs baseline: 2.5798x; 2.5798x over previous
//
#include <hip/hip_runtime.h>
#include <math.h>

#define NX 192
#define NY 192
#define NZ 96
#define NV 4
#define VOL (NZ * NY * NX)      /* 3,538,944 */
#define NTOT (NV * VOL)         /* 14,155,776 */
#define YS NX
#define ZS (NY * NX)

#define TX 32
#define TY 8
#define ZCH 24                   /* z-chunk per block: 4 chunks */
#define AW (TX + 4)              /* 36 */
#define AH (TY + 4)              /* 12 */
#define EW (TX + 2)              /* 34 */
#define EH (TY + 2)              /* 10 */

__global__ void extract_kernel(const float* __restrict__ pred,
                               const float* __restrict__ target,
                               float* __restrict__ cur) {
    int i = blockIdx.x * blockDim.x + threadIdx.x;
    if (i >= NTOT) return;
    int v = i / VOL;
    int p = i - v * VOL;
    int b = v & 1;
    const float* src = (v < 2) ? pred : target;
    cur[i] = src[(size_t)(b * 2 + 1) * VOL + p];
}

// Fused per-iteration kernel: E = erode(A) (written to global, next iter's A),
// D = dilate(E), delta = relu(A - D), skel += relu(delta - skel*delta).
// Each block: (TX x TY) tile, streams ZCH z-planes using LDS ring buffers.
__global__ __launch_bounds__(256) void fused_kernel(const float* __restrict__ A,
                                                    float* __restrict__ E,
                                                    float* __restrict__ skel) {
    __shared__ float As[3][AH][AW];   // A planes, halo 2, +inf outside volume
    __shared__ float Es[3][EH][EW];   // E planes, halo 1, -inf outside volume
    __shared__ float Ms[EH][EW];      // z-max of 3 E planes

    const int tid = threadIdx.x;
    const int x0 = blockIdx.x * TX;
    const int y0 = blockIdx.y * TY;
    const int v  = blockIdx.z >> 2;
    const int z0 = (blockIdx.z & 3) * ZCH;
    const int z1 = z0 + ZCH;

    const float* Av = A + (size_t)v * VOL;
    float* Ev = E + (size_t)v * VOL;
    float* Sv = skel + (size_t)v * VOL;

    // stage A plane z into ring slot (with +inf padding outside volume)
    auto stage = [&](int z) {
        int slot = ((z % 3) + 3) % 3;
        float* dst = &As[slot][0][0];
        if (z < 0 || z >= NZ) {
            for (int j = tid; j < AH * AW; j += 256) dst[j] = INFINITY;
        } else {
            const float* P = Av + (size_t)z * ZS;
            for (int j = tid; j < AH * AW; j += 256) {
                int ay = j / AW, ax = j - ay * AW;
                int gy = y0 - 2 + ay, gx = x0 - 2 + ax;
                float val = INFINITY;
                if (gy >= 0 && gy < NY && gx >= 0 && gx < NX)
                    val = P[gy * YS + gx];
                dst[j] = val;
            }
        }
    };

    // compute E plane z into ring slot from A ring; optionally write interior
    auto eplane = [&](int z, bool wr) {
        int slot = ((z % 3) + 3) % 3;
        float* dst = &Es[slot][0][0];
        if (z < 0 || z >= NZ) {
            for (int j = tid; j < EH * EW; j += 256) dst[j] = -INFINITY;
            return;
        }
        const int sc = z % 3;
        const int sm = ((z - 1) % 3 + 3) % 3;
        const int sp = (z + 1) % 3;
        for (int j = tid; j < EH * EW; j += 256) {
            int ey = j / EW, ex = j - ey * EW;
            int gy = y0 - 1 + ey, gx = x0 - 1 + ex;
            float m;
            if (gy < 0 || gy >= NY || gx < 0 || gx >= NX) {
                m = -INFINITY;
            } else {
                int ay = ey + 1, ax = ex + 1;
                m = As[sc][ay][ax];
                m = fminf(m, As[sc][ay][ax - 1]);
                m = fminf(m, As[sc][ay][ax + 1]);
                m = fminf(m, As[sc][ay - 1][ax]);
                m = fminf(m, As[sc][ay + 1][ax]);
                m = fminf(m, As[sm][ay][ax]);
                m = fminf(m, As[sp][ay][ax]);
                if (wr && ey >= 1 && ey <= TY && ex >= 1 && ex <= TX)
                    Ev[(size_t)z * ZS + gy * YS + gx] = m;
            }
            dst[j] = m;
        }
    };

    // ---- prime: A(z0-2..z0), E(z0-1); then A(z0+1), E(z0) ----
    stage(z0 - 2);
    stage(z0 - 1);
    stage(z0);
    __syncthreads();
    eplane(z0 - 1, false);
    __syncthreads();
    stage(z0 + 1);
    __syncthreads();
    eplane(z0, z0 == 0);   // chunk 0 owns writing plane 0
    __syncthreads();

    const int ty = tid >> 5;
    const int tx = tid & 31;

    // ---- main loop over output planes z in [z0, z1) ----
    for (int z = z0; z < z1; ++z) {
        stage(z + 2);
        __syncthreads();
        eplane(z + 1, true);
        __syncthreads();
        {   // M = z-max of E(z-1), E(z), E(z+1)
            const float* e0 = &Es[((z - 1) % 3 + 3) % 3][0][0];
            const float* e1 = &Es[z % 3][0][0];
            const float* e2 = &Es[(z + 1) % 3][0][0];
            float* mm = &Ms[0][0];
            for (int j = tid; j < EH * EW; j += 256)
                mm[j] = fmaxf(fmaxf(e0[j], e1[j]), e2[j]);
        }
        __syncthreads();
        {   // D = 3x3 in-plane max of M; delta; skel RMW
            int ey = ty + 1, ex = tx + 1;
            float d =          Ms[ey - 1][ex - 1];
            d = fmaxf(d, Ms[ey - 1][ex]);
            d = fmaxf(d, Ms[ey - 1][ex + 1]);
            d = fmaxf(d, Ms[ey][ex - 1]);
            d = fmaxf(d, Ms[ey][ex]);
            d = fmaxf(d, Ms[ey][ex + 1]);
            d = fmaxf(d, Ms[ey + 1][ex - 1]);
            d = fmaxf(d, Ms[ey + 1][ex]);
            d = fmaxf(d, Ms[ey + 1][ex + 1]);
            float av = As[z % 3][ty + 2][tx + 2];
            float delta = fmaxf(av - d, 0.0f);
            size_t gi = (size_t)z * ZS + (size_t)(y0 + ty) * YS + (x0 + tx);
            float s = Sv[gi];
            Sv[gi] = s + fmaxf(delta - s * delta, 0.0f);
        }
        __syncthreads();
    }
}

__global__ void reduce_kernel(const float* __restrict__ skel,
                              const float* __restrict__ pred,
                              const float* __restrict__ target,
                              double* __restrict__ sums) {
    double acc[4] = {0.0, 0.0, 0.0, 0.0};
    for (int i = blockIdx.x * blockDim.x + threadIdx.x; i < NTOT;
         i += gridDim.x * blockDim.x) {
        int v = i / VOL;
        int p = i - v * VOL;
        int b = v & 1;
        size_t inoff = (size_t)(b * 2 + 1) * VOL + p;
        float s = skel[i];
        if (v < 2) {
            acc[0] += (double)(s * target[inoff]);
            acc[1] += (double)s;
        } else {
            acc[2] += (double)(s * pred[inoff]);
            acc[3] += (double)s;
        }
    }
#pragma unroll
    for (int off = 32; off > 0; off >>= 1) {
#pragma unroll
        for (int k = 0; k < 4; ++k) acc[k] += __shfl_down(acc[k], off, 64);
    }
    __shared__ double sm[4][4];
    int lane = threadIdx.x & 63;
    int wid = threadIdx.x >> 6;
    if (lane == 0) {
#pragma unroll
        for (int k = 0; k < 4; ++k) sm[wid][k] = acc[k];
    }
    __syncthreads();
    if (threadIdx.x == 0) {
#pragma unroll
        for (int k = 0; k < 4; ++k) {
            double t = sm[0][k] + sm[1][k] + sm[2][k] + sm[3][k];
            atomicAdd(&sums[k], t);
        }
    }
}

__global__ void final_kernel(const double* __restrict__ sums,
                             float* __restrict__ out) {
    if (threadIdx.x == 0 && blockIdx.x == 0) {
        const double SM = 1e-5;
        double tprec = (sums[0] + SM) / (sums[1] + SM);
        double tsens = (sums[2] + SM) / (sums[3] + SM);
        double cl = 2.0 * tprec * tsens / (tprec + tsens + SM);
        out[0] = (float)(1.0 - cl);
    }
}

extern "C" void kernel_launch(void* const* d_in, const int* in_sizes, int n_in,
                              void* d_out, int out_size, void* d_ws, size_t ws_size,
                              hipStream_t stream) {
    const float* pred = (const float*)d_in[0];
    const float* target = (const float*)d_in[1];
    float* out = (float*)d_out;

    float* cur = (float*)d_ws;
    float* ero = cur + NTOT;
    float* skel = ero + NTOT;
    double* sums = (double*)(skel + NTOT);

    hipMemsetAsync(skel, 0, (size_t)NTOT * sizeof(float), stream);
    hipMemsetAsync(sums, 0, 4 * sizeof(double), stream);

    const int threads = 256;
    const int grid1 = (NTOT + threads - 1) / threads;
    extract_kernel<<<grid1, threads, 0, stream>>>(pred, target, cur);

    dim3 fgrid(NX / TX, NY / TY, NV * 4);   // 6 x 24 x 16 = 2304 blocks
    float* Abuf = cur;
    float* Ebuf = ero;
    for (int it = 0; it <= 50; ++it) {
        fused_kernel<<<fgrid, 256, 0, stream>>>(Abuf, Ebuf, skel);
        float* tmp = Abuf; Abuf = Ebuf; Ebuf = tmp;
    }

    reduce_kernel<<<2048, 256, 0, stream>>>(skel, pred, target, sums);
    final_kernel<<<1, 64, 0, stream>>>(sums, out);
}

// Round 3
// 2919.862 us; speedup vs baseline: 4.5216x; 1.7527x over previous
//
#include <hip/hip_runtime.h>
#include <math.h>

#define NX 192
#define NY 192
#define NZ 96
#define NV 4
#define VOL (NZ * NY * NX)      /* 3,538,944 */
#define NTOT (NV * VOL)         /* 14,155,776 */
#define VOL4 (VOL / 4)
#define NTOT4 (NTOT / 4)
#define YS NX
#define ZS (NY * NX)

#define TX 48                    /* x tile (12 float4 groups) */
#define TY 16                    /* y tile */
#define ZCH 24                   /* z planes per chunk (4 chunks) */
#define NG 14                    /* x groups incl halo: cells [-4, TX+4) */
#define AROWS (TY + 4)           /* A rows: gy in [y0-2, y0+TY+2) */
#define EROWS (TY + 2)           /* E/M rows: gy in [y0-1, y0+TY+1) */
#define AJOBS (AROWS * NG)       /* 280 */
#define EJOBS (EROWS * NG)       /* 252 */
#define UJOBS (TY * (TX / 4))    /* 192 */

__device__ __forceinline__ float4 min4(float4 a, float4 b) {
    return make_float4(fminf(a.x, b.x), fminf(a.y, b.y),
                       fminf(a.z, b.z), fminf(a.w, b.w));
}
__device__ __forceinline__ float4 max4(float4 a, float4 b) {
    return make_float4(fmaxf(a.x, b.x), fmaxf(a.y, b.y),
                       fmaxf(a.z, b.z), fmaxf(a.w, b.w));
}
// window-3 max over cells [a, b.x..b.w, c] producing max of each 3-window
__device__ __forceinline__ float4 win3max(float a, float4 b, float c) {
    return make_float4(fmaxf(fmaxf(a, b.x), b.y),
                       fmaxf(fmaxf(b.x, b.y), b.z),
                       fmaxf(fmaxf(b.y, b.z), b.w),
                       fmaxf(fmaxf(b.z, b.w), c));
}

__global__ void extract_kernel(const float* __restrict__ pred,
                               const float* __restrict__ target,
                               float* __restrict__ cur) {
    int i = blockIdx.x * blockDim.x + threadIdx.x;
    if (i >= NTOT4) return;
    int v = i / VOL4;
    int p = i - v * VOL4;
    int b = v & 1;
    const float4* src = (const float4*)((v < 2) ? pred : target);
    ((float4*)cur)[i] = src[(size_t)(b * 2 + 1) * VOL4 + p];
}

// Fused iteration: E = erode(A) (written out as next iter's input),
// D = dilate3x3x3(E), delta = relu(A-D), skel += relu(delta - skel*delta).
// Block tile: TX x TY x ZCH, z-streamed with LDS rings, float4 vectorized.
__global__ __launch_bounds__(256, 3) void fused_kernel(const float* __restrict__ A,
                                                       float* __restrict__ E,
                                                       float* __restrict__ skel) {
    __shared__ float4 As[4][AROWS][NG];   // +inf outside volume
    __shared__ float4 Es[3][EROWS][NG];   // -inf outside volume
    __shared__ float4 Ms[EROWS][NG];

    const int tid = threadIdx.x;
    const int x0 = blockIdx.x * TX;
    const int y0 = blockIdx.y * TY;
    const int v  = blockIdx.z >> 2;
    const int z0 = (blockIdx.z & 3) * ZCH;
    const int z1 = z0 + ZCH;

    const float* Av = A + (size_t)v * VOL;
    float* Ev = E + (size_t)v * VOL;
    float* Sv = skel + (size_t)v * VOL;

    const float4 PINF4 = make_float4(INFINITY, INFINITY, INFINITY, INFINITY);
    const float4 NINF4 = make_float4(-INFINITY, -INFINITY, -INFINITY, -INFINITY);

    // stage A plane z into 4-ring slot
    auto stageA = [&](int z) {
        int slot = (z + 8) & 3;
        float4* dst = &As[slot][0][0];
        if (z < 0 || z >= NZ) {
            for (int j = tid; j < AJOBS; j += 256) dst[j] = PINF4;
        } else {
            const float* P = Av + (size_t)z * ZS;
            for (int j = tid; j < AJOBS; j += 256) {
                int r = j / NG, g = j - r * NG;
                int gy = y0 - 2 + r;
                int gx0 = x0 - 4 + 4 * g;
                float4 val = PINF4;
                if (gy >= 0 && gy < NY && gx0 >= 0 && gx0 < NX)
                    val = *(const float4*)(P + gy * YS + gx0);
                dst[j] = val;
            }
        }
    };

    // compute erode plane z into 3-ring slot; write interior to global if owned
    auto eplane = [&](int z) {
        int es = (z + 9) % 3;
        float4* dst = &Es[es][0][0];
        if (z < 0 || z >= NZ) {
            for (int j = tid; j < EJOBS; j += 256) dst[j] = NINF4;
            return;
        }
        const int sc = (z + 8) & 3;
        const int sm = (z + 7) & 3;
        const int sp = (z + 9) & 3;
        const bool wr = (z >= z0 && z < z1);
        for (int j = tid; j < EJOBS; j += 256) {
            int r = j / NG, g = j - r * NG;         // E row r <-> gy = y0-1+r ; A row r+1
            float4 c  = As[sc][r + 1][g];
            float4 yl = As[sc][r][g];
            float4 yh = As[sc][r + 2][g];
            float4 zl = As[sm][r + 1][g];
            float4 zh = As[sp][r + 1][g];
            float pw = (g > 0)      ? As[sc][r + 1][g - 1].w : INFINITY;
            float nx = (g < NG - 1) ? As[sc][r + 1][g + 1].x : INFINITY;
            float4 xl = make_float4(pw, c.x, c.y, c.z);
            float4 xr = make_float4(c.y, c.z, c.w, nx);
            float4 m = min4(c, xl);
            m = min4(m, xr);
            m = min4(m, yl);
            m = min4(m, yh);
            m = min4(m, zl);
            m = min4(m, zh);
            int gy = y0 - 1 + r;
            int gx0 = x0 - 4 + 4 * g;
            if (gy < 0 || gy >= NY || gx0 < 0 || gx0 >= NX) m = NINF4;
            dst[j] = m;
            if (wr && r >= 1 && r <= TY && g >= 1 && g <= NG - 2)
                *(float4*)(Ev + (size_t)z * ZS + gy * YS + gx0) = m;
        }
    };

    // ---- prime ----
    stageA(z0 - 2); stageA(z0 - 1); stageA(z0); stageA(z0 + 1);
    __syncthreads();
    eplane(z0 - 1);
    eplane(z0);
    __syncthreads();
    stageA(z0 + 2);
    __syncthreads();

    // ---- main loop over output planes ----
    for (int z = z0; z < z1; ++z) {
        stageA(z + 3);
        eplane(z + 1);
        __syncthreads();
        {   // Ms = z-max of E(z-1), E(z), E(z+1)
            const float4* e0 = &Es[(z + 8) % 3][0][0];
            const float4* e1 = &Es[(z + 9) % 3][0][0];
            const float4* e2 = &Es[(z + 10) % 3][0][0];
            float4* mm = &Ms[0][0];
            for (int j = tid; j < EJOBS; j += 256)
                mm[j] = max4(max4(e0[j], e1[j]), e2[j]);
        }
        __syncthreads();
        if (tid < UJOBS) {   // 3x3 in-plane max of Ms, delta, skel RMW
            int r = tid / (TX / 4);
            int gp = tid - r * (TX / 4);
            int g = gp + 1;
            float4 d = NINF4;
#pragma unroll
            for (int dy = 0; dy < 3; ++dy) {
                float a  = Ms[r + dy][g - 1].w;
                float4 b = Ms[r + dy][g];
                float c  = Ms[r + dy][g + 1].x;
                d = max4(d, win3max(a, b, c));
            }
            float4 av = As[(z + 8) & 3][r + 2][g];
            float4 delta = make_float4(fmaxf(av.x - d.x, 0.0f),
                                       fmaxf(av.y - d.y, 0.0f),
                                       fmaxf(av.z - d.z, 0.0f),
                                       fmaxf(av.w - d.w, 0.0f));
            size_t gi = (size_t)z * ZS + (size_t)(y0 + r) * YS + (x0 + gp * 4);
            float4* sp4 = (float4*)(Sv + gi);
            float4 s = *sp4;
            s.x += fmaxf(delta.x - s.x * delta.x, 0.0f);
            s.y += fmaxf(delta.y - s.y * delta.y, 0.0f);
            s.z += fmaxf(delta.z - s.z * delta.z, 0.0f);
            s.w += fmaxf(delta.w - s.w * delta.w, 0.0f);
            *sp4 = s;
        }
        __syncthreads();
    }
}

__global__ void reduce_kernel(const float* __restrict__ skel,
                              const float* __restrict__ pred,
                              const float* __restrict__ target,
                              double* __restrict__ sums) {
    double acc[4] = {0.0, 0.0, 0.0, 0.0};
    const float4* sk4 = (const float4*)skel;
    const float4* p4 = (const float4*)pred;
    const float4* t4 = (const float4*)target;
    for (int i = blockIdx.x * blockDim.x + threadIdx.x; i < NTOT4;
         i += gridDim.x * blockDim.x) {
        int v = i / VOL4;
        int p = i - v * VOL4;
        int b = v & 1;
        size_t inoff = (size_t)(b * 2 + 1) * VOL4 + p;
        float4 s = sk4[i];
        float4 o = (v < 2) ? t4[inoff] : p4[inoff];
        float dot = s.x * o.x + s.y * o.y + s.z * o.z + s.w * o.w;
        float ssum = s.x + s.y + s.z + s.w;
        if (v < 2) {
            acc[0] += (double)dot;
            acc[1] += (double)ssum;
        } else {
            acc[2] += (double)dot;
            acc[3] += (double)ssum;
        }
    }
#pragma unroll
    for (int off = 32; off > 0; off >>= 1) {
#pragma unroll
        for (int k = 0; k < 4; ++k) acc[k] += __shfl_down(acc[k], off, 64);
    }
    __shared__ double sm[4][4];
    int lane = threadIdx.x & 63;
    int wid = threadIdx.x >> 6;
    if (lane == 0) {
#pragma unroll
        for (int k = 0; k < 4; ++k) sm[wid][k] = acc[k];
    }
    __syncthreads();
    if (threadIdx.x == 0) {
#pragma unroll
        for (int k = 0; k < 4; ++k) {
            double t = sm[0][k] + sm[1][k] + sm[2][k] + sm[3][k];
            atomicAdd(&sums[k], t);
        }
    }
}

__global__ void final_kernel(const double* __restrict__ sums,
                             float* __restrict__ out) {
    if (threadIdx.x == 0 && blockIdx.x == 0) {
        const double SM = 1e-5;
        double tprec = (sums[0] + SM) / (sums[1] + SM);
        double tsens = (sums[2] + SM) / (sums[3] + SM);
        double cl = 2.0 * tprec * tsens / (tprec + tsens + SM);
        out[0] = (float)(1.0 - cl);
    }
}

extern "C" void kernel_launch(void* const* d_in, const int* in_sizes, int n_in,
                              void* d_out, int out_size, void* d_ws, size_t ws_size,
                              hipStream_t stream) {
    const float* pred = (const float*)d_in[0];
    const float* target = (const float*)d_in[1];
    float* out = (float*)d_out;

    float* cur = (float*)d_ws;
    float* ero = cur + NTOT;
    float* skel = ero + NTOT;
    double* sums = (double*)(skel + NTOT);

    hipMemsetAsync(skel, 0, (size_t)NTOT * sizeof(float), stream);
    hipMemsetAsync(sums, 0, 4 * sizeof(double), stream);

    extract_kernel<<<NTOT4 / 256, 256, 0, stream>>>(pred, target, cur);

    dim3 fgrid(NX / TX, NY / TY, NV * 4);   // 4 x 12 x 16 = 768 blocks (3/CU)
    float* Abuf = cur;
    float* Ebuf = ero;
    for (int it = 0; it <= 50; ++it) {
        fused_kernel<<<fgrid, 256, 0, stream>>>(Abuf, Ebuf, skel);
        float* tmp = Abuf; Abuf = Ebuf; Ebuf = tmp;
    }

    reduce_kernel<<<1024, 256, 0, stream>>>(skel, pred, target, sums);
    final_kernel<<<1, 64, 0, stream>>>(sums, out);
}